// Round 6
// baseline (264.123 us; speedup 1.0000x reference)
//
#include <hip/hip_runtime.h>
#include <hip/hip_bf16.h>

typedef __attribute__((ext_vector_type(4))) float f32x4;
typedef __attribute__((ext_vector_type(8))) short bf16x8;
typedef __attribute__((ext_vector_type(4))) short bf16x4;

static constexpr int S = 2048;
static constexpr int D = 64;
static constexpr int QB = 64;    // Q rows per block (16 per wave)
static constexpr int KVB = 64;   // KV rows per tile
static constexpr float SCALE = 0.125f;           // 1/sqrt(64)
static constexpr float LOG2E = 1.44269504088896340736f;

__device__ __forceinline__ unsigned short f2bf(float f) {
    unsigned int u = __builtin_bit_cast(unsigned int, f);
    u += 0x7fffu + ((u >> 16) & 1u);             // round-to-nearest-even
    return (unsigned short)(u >> 16);
}
__device__ __forceinline__ float bf2f(unsigned short h) {
    unsigned int u = ((unsigned int)h) << 16;
    return __builtin_bit_cast(float, u);
}
// XOR swizzle at 16B granularity: index in shorts, rows of 64 shorts (128B)
__device__ __forceinline__ int swz(int r, int c) {
    return r * 64 + (c ^ ((r & 7) << 3));
}

__global__ __launch_bounds__(256, 2) void attn_fwd(const float* __restrict__ x,
                                                   float* __restrict__ out) {
    __shared__ __align__(16) unsigned short Khi[KVB * D];
    __shared__ __align__(16) unsigned short Klo[KVB * D];
    __shared__ __align__(16) unsigned short Vt[D * KVB];   // V^T: [d][kv]
    __shared__ __align__(16) unsigned short Pl[4 * 16 * KVB]; // per-wave P tile

    const int tid  = threadIdx.x;
    const int lane = tid & 63;
    const int wave = tid >> 6;
    const int l15  = lane & 15;
    const int g    = lane >> 4;

    const int pr = blockIdx.x & 31;   // pair = h*2 + b
    const int qt = blockIdx.x >> 5;   // q-tile index
    const float* __restrict__ base = x + (size_t)pr * (S * D);

    // ---- Q fragments (hi/lo bf16), registers for the whole kernel
    bf16x8 a_hi[2], a_lo[2];
    const int qrow = qt * QB + wave * 16 + l15;
    #pragma unroll
    for (int c = 0; c < 2; ++c) {
        const float* qp = base + qrow * D + c * 32 + g * 8;
        float4 q0 = *(const float4*)(qp);
        float4 q1 = *(const float4*)(qp + 4);
        float qv[8] = {q0.x, q0.y, q0.z, q0.w, q1.x, q1.y, q1.z, q1.w};
        bf16x8 hv, lv;
        #pragma unroll
        for (int i = 0; i < 8; ++i) {
            unsigned short hb = f2bf(qv[i]);
            hv[i] = (short)hb;
            lv[i] = (short)f2bf(qv[i] - bf2f(hb));
        }
        a_hi[c] = hv;
        a_lo[c] = lv;
    }

    f32x4 O[4];
    f32x4 zero4 = {0.f, 0.f, 0.f, 0.f};
    #pragma unroll
    for (int n = 0; n < 4; ++n) O[n] = zero4;
    float m_run[4] = {-INFINITY, -INFINITY, -INFINITY, -INFINITY};
    float l_run[4] = {0.f, 0.f, 0.f, 0.f};

    for (int kv = 0; kv < S; kv += KVB) {
        // ---- stage K (hi/lo, row-major swizzled) + V^T (swizzled)
        #pragma unroll
        for (int it = 0; it < 4; ++it) {
            int o = it * 1024 + tid * 4;
            int r = o >> 6;       // kv row within tile
            int c = o & 63;       // feature
            float4 v = *(const float4*)(base + (size_t)(kv + r) * D + c);
            float vv[4] = {v.x, v.y, v.z, v.w};
            unsigned short hb[4];
            bf16x4 hvv, lvv;
            #pragma unroll
            for (int i = 0; i < 4; ++i) {
                hb[i] = f2bf(vv[i]);
                hvv[i] = (short)hb[i];
                lvv[i] = (short)f2bf(vv[i] - bf2f(hb[i]));
            }
            int idx = swz(r, c);
            *(bf16x4*)(&Khi[idx]) = hvv;
            *(bf16x4*)(&Klo[idx]) = lvv;
            #pragma unroll
            for (int i = 0; i < 4; ++i) Vt[swz(c + i, r)] = hb[i];
        }
        __syncthreads();

        // ---- S = Q K^T with hi/lo compensation (f32 accum)
        f32x4 st[4];
        #pragma unroll
        for (int n = 0; n < 4; ++n) {
            f32x4 acc = zero4;
            #pragma unroll
            for (int c = 0; c < 2; ++c) {
                int krow = n * 16 + l15;
                int col = c * 32 + g * 8;
                bf16x8 bh = *(const bf16x8*)(&Khi[swz(krow, col)]);
                bf16x8 bl = *(const bf16x8*)(&Klo[swz(krow, col)]);
                acc = __builtin_amdgcn_mfma_f32_16x16x32_bf16(a_lo[c], bh, acc, 0, 0, 0);
                acc = __builtin_amdgcn_mfma_f32_16x16x32_bf16(a_hi[c], bl, acc, 0, 0, 0);
                acc = __builtin_amdgcn_mfma_f32_16x16x32_bf16(a_hi[c], bh, acc, 0, 0, 0);
            }
            st[n] = acc;
        }

        // ---- online softmax; rows of this wave's tile: g*4 + j
        #pragma unroll
        for (int j = 0; j < 4; ++j) {
            float t[4];
            #pragma unroll
            for (int n = 0; n < 4; ++n) t[n] = st[n][j] * SCALE;
            float mx = fmaxf(fmaxf(t[0], t[1]), fmaxf(t[2], t[3]));
            #pragma unroll
            for (int w = 1; w <= 8; w <<= 1) mx = fmaxf(mx, __shfl_xor(mx, w, 64));
            float M = fmaxf(m_run[j], mx);
            float f = exp2f((m_run[j] - M) * LOG2E);
            m_run[j] = M;
            float p[4], sum = 0.f;
            #pragma unroll
            for (int n = 0; n < 4; ++n) {
                p[n] = exp2f((t[n] - M) * LOG2E);
                sum += p[n];
            }
            #pragma unroll
            for (int w = 1; w <= 8; w <<= 1) sum += __shfl_xor(sum, w, 64);
            l_run[j] = l_run[j] * f + sum;
            #pragma unroll
            for (int n = 0; n < 4; ++n) O[n][j] *= f;
            int r = g * 4 + j;
            #pragma unroll
            for (int n = 0; n < 4; ++n)
                Pl[wave * 1024 + r * 64 + ((n * 16 + l15) ^ ((r & 7) << 3))] = f2bf(p[n]);
        }
        __syncthreads();   // round-0 safety: Pl write -> read ordering

        // ---- O += P V   (A = P rows from Pl, B = V columns from Vt rows)
        #pragma unroll
        for (int c = 0; c < 2; ++c) {
            int pcol = c * 32 + g * 8;
            bf16x8 pa = *(const bf16x8*)(&Pl[wave * 1024 + swz(l15, pcol)]);
            #pragma unroll
            for (int n = 0; n < 4; ++n) {
                bf16x8 vb = *(const bf16x8*)(&Vt[swz(n * 16 + l15, pcol)]);
                O[n] = __builtin_amdgcn_mfma_f32_16x16x32_bf16(pa, vb, O[n], 0, 0, 0);
            }
        }
        __syncthreads();   // protect K/Vt before restage
    }

    // ---- epilogue: normalize and store (f32)
    const int hh = pr >> 1, bb = pr & 1;
    #pragma unroll
    for (int j = 0; j < 4; ++j) {
        float inv = 1.0f / l_run[j];
        int s = qt * QB + wave * 16 + g * 4 + j;
        float* op = out + (((size_t)(hh * S + s)) * 2 + bb) * 64;
        #pragma unroll
        for (int n = 0; n < 4; ++n) op[n * 16 + l15] = O[n][j] * inv;
    }
}

extern "C" void kernel_launch(void* const* d_in, const int* in_sizes, int n_in,
                              void* d_out, int out_size, void* d_ws, size_t ws_size,
                              hipStream_t stream) {
    (void)in_sizes; (void)n_in; (void)out_size; (void)d_ws; (void)ws_size;
    const float* x = (const float*)d_in[0];
    float* out = (float*)d_out;
    attn_fwd<<<dim3((S / QB) * 32), dim3(256), 0, stream>>>(x, out);
}

// Round 7
// 210.985 us; speedup vs baseline: 1.2519x; 1.2519x over previous
//
#include <hip/hip_runtime.h>
#include <hip/hip_bf16.h>

typedef __attribute__((ext_vector_type(4))) float f32x4;
typedef __attribute__((ext_vector_type(8))) short bf16x8;
typedef __attribute__((ext_vector_type(4))) short bf16x4;

static constexpr int S = 2048;
static constexpr int D = 64;
static constexpr int QB = 64;    // Q rows per block (16 per wave)
static constexpr int KVB = 64;   // KV rows per tile
static constexpr float SCALE = 0.125f;           // 1/sqrt(64)
static constexpr float LOG2E = 1.44269504088896340736f;
static constexpr size_t ARR = (size_t)32 * 32 * 4096;   // shorts per ws array
static constexpr size_t WS_NEED = 3 * ARR * sizeof(unsigned short); // 25,165,824 B

__device__ __forceinline__ unsigned short f2bf(float f) {
    unsigned int u = __builtin_bit_cast(unsigned int, f);
    u += 0x7fffu + ((u >> 16) & 1u);             // round-to-nearest-even
    return (unsigned short)(u >> 16);
}
__device__ __forceinline__ float bf2f(unsigned short h) {
    unsigned int u = ((unsigned int)h) << 16;
    return __builtin_bit_cast(float, u);
}
// XOR swizzle at 16B granularity: index in shorts, rows of 64 shorts (128B)
__device__ __forceinline__ int swz(int r, int c) {
    return r * 64 + (c ^ ((r & 7) << 3));
}
__device__ __forceinline__ void gload16(const void* g, void* l) {
    __builtin_amdgcn_global_load_lds(
        (const __attribute__((address_space(1))) unsigned int*)g,
        (__attribute__((address_space(3))) unsigned int*)l, 16, 0, 0);
}

// ---------------- prepass: x(f32) -> Khi/Klo (row-major) + Vt (transposed), bf16,
// tile-contiguous [pair*32+t][64][64]. Run once per call; ~80 MB traffic.
__global__ __launch_bounds__(256) void prep_convert(const float* __restrict__ x,
        unsigned short* __restrict__ Khi_g, unsigned short* __restrict__ Klo_g,
        unsigned short* __restrict__ Vt_g) {
    __shared__ unsigned short Lhi[64 * 65];
    const int tid = threadIdx.x;
    const int blk = blockIdx.x;          // pr*32 + t  (x tile base == blk*4096)
    const int r  = tid >> 2;
    const int c0 = (tid & 3) << 4;
    const float* rp = x + (size_t)blk * 4096 + r * 64 + c0;
    unsigned short hi[16], lo[16];
    #pragma unroll
    for (int i = 0; i < 16; i += 4) {
        float4 f = *(const float4*)(rp + i);
        float fv[4] = {f.x, f.y, f.z, f.w};
        #pragma unroll
        for (int k = 0; k < 4; ++k) {
            hi[i + k] = f2bf(fv[k]);
            lo[i + k] = f2bf(fv[k] - bf2f(hi[i + k]));
        }
    }
    bf16x8 h0, h1, l0, l1;
    #pragma unroll
    for (int i = 0; i < 8; ++i) {
        h0[i] = (short)hi[i]; h1[i] = (short)hi[i + 8];
        l0[i] = (short)lo[i]; l1[i] = (short)lo[i + 8];
    }
    const size_t ob = (size_t)blk * 4096 + r * 64 + c0;
    *(bf16x8*)&Khi_g[ob] = h0;  *(bf16x8*)&Khi_g[ob + 8] = h1;
    *(bf16x8*)&Klo_g[ob] = l0;  *(bf16x8*)&Klo_g[ob + 8] = l1;
    #pragma unroll
    for (int i = 0; i < 16; ++i) Lhi[r * 65 + c0 + i] = hi[i];
    __syncthreads();
    // transpose within the 64x64 tile: this thread emits row d=r of Vt, cols c0..c0+15
    unsigned short tv[16];
    #pragma unroll
    for (int i = 0; i < 16; ++i) tv[i] = Lhi[(c0 + i) * 65 + r];
    bf16x8 t0, t1;
    #pragma unroll
    for (int i = 0; i < 8; ++i) { t0[i] = (short)tv[i]; t1[i] = (short)tv[i + 8]; }
    *(bf16x8*)&Vt_g[ob] = t0;  *(bf16x8*)&Vt_g[ob + 8] = t1;
}

// ---------------- main attention kernel: stages pre-converted tiles via
// global_load_lds (width 16, pre-swizzled global source -> linear LDS dest).
__global__ __launch_bounds__(256, 2) void attn_fwd2(
        const unsigned short* __restrict__ Khi_g,
        const unsigned short* __restrict__ Klo_g,
        const unsigned short* __restrict__ Vt_g,
        float* __restrict__ out) {
    __shared__ __align__(16) unsigned short Khi[KVB * D];
    __shared__ __align__(16) unsigned short Klo[KVB * D];
    __shared__ __align__(16) unsigned short Vt[D * KVB];
    __shared__ __align__(16) unsigned short Pl[4 * 16 * KVB];

    const int tid  = threadIdx.x;
    const int lane = tid & 63;
    const int wave = tid >> 6;
    const int l15  = lane & 15;
    const int g    = lane >> 4;
    const int pr = blockIdx.x & 31;
    const int qt = blockIdx.x >> 5;

    // ---- Q fragments straight from pre-converted arrays (no VALU convert)
    const size_t qbase = ((size_t)pr * 32 + qt) * 4096 + (size_t)(wave * 16 + l15) * 64 + g * 8;
    bf16x8 a_hi[2], a_lo[2];
    a_hi[0] = *(const bf16x8*)&Khi_g[qbase];
    a_hi[1] = *(const bf16x8*)&Khi_g[qbase + 32];
    a_lo[0] = *(const bf16x8*)&Klo_g[qbase];
    a_lo[1] = *(const bf16x8*)&Klo_g[qbase + 32];

    f32x4 O[4];
    f32x4 zero4 = {0.f, 0.f, 0.f, 0.f};
    #pragma unroll
    for (int n = 0; n < 4; ++n) O[n] = zero4;
    float m_run[4] = {-INFINITY, -INFINITY, -INFINITY, -INFINITY};
    float l_run[4] = {0.f, 0.f, 0.f, 0.f};

    // staging source offset (bytes) for this thread's lane within its wave's chunk:
    // LDS slot (r = ch*8 + l>>3, cl = (l&7)*8) <- global short r*64 + (cl ^ ((r&7)<<3))
    const int go = wave * 1024 + (lane >> 3) * 128 + (((lane & 7) ^ (lane >> 3)) << 4);
    char* KhiL = (char*)Khi + wave * 1024;
    char* KloL = (char*)Klo + wave * 1024;
    char* VtL  = (char*)Vt  + wave * 1024;

    for (int t = 0; t < 32; ++t) {
        const size_t tb = ((size_t)pr * 32 + t) * 8192;   // tile base, bytes
        const char* kh = (const char*)Khi_g + tb;
        const char* kl = (const char*)Klo_g + tb;
        const char* vt = (const char*)Vt_g + tb;
        gload16(kh + go,        KhiL);
        gload16(kh + go + 4096, KhiL + 4096);
        gload16(kl + go,        KloL);
        gload16(kl + go + 4096, KloL + 4096);
        gload16(vt + go,        VtL);
        gload16(vt + go + 4096, VtL + 4096);
        __syncthreads();   // drains vmcnt(0): all waves' staging complete

        // ---- S = Q K^T with hi/lo compensation (f32 accum)
        f32x4 st[4];
        #pragma unroll
        for (int n = 0; n < 4; ++n) {
            f32x4 acc = zero4;
            #pragma unroll
            for (int c = 0; c < 2; ++c) {
                int krow = n * 16 + l15;
                int col = c * 32 + g * 8;
                bf16x8 bh = *(const bf16x8*)(&Khi[swz(krow, col)]);
                bf16x8 bl = *(const bf16x8*)(&Klo[swz(krow, col)]);
                acc = __builtin_amdgcn_mfma_f32_16x16x32_bf16(a_lo[c], bh, acc, 0, 0, 0);
                acc = __builtin_amdgcn_mfma_f32_16x16x32_bf16(a_hi[c], bl, acc, 0, 0, 0);
                acc = __builtin_amdgcn_mfma_f32_16x16x32_bf16(a_hi[c], bh, acc, 0, 0, 0);
            }
            st[n] = acc;
        }

        // ---- online softmax; rows of this wave's tile: g*4 + j
        #pragma unroll
        for (int j = 0; j < 4; ++j) {
            float tt[4];
            #pragma unroll
            for (int n = 0; n < 4; ++n) tt[n] = st[n][j] * SCALE;
            float mx = fmaxf(fmaxf(tt[0], tt[1]), fmaxf(tt[2], tt[3]));
            #pragma unroll
            for (int w = 1; w <= 8; w <<= 1) mx = fmaxf(mx, __shfl_xor(mx, w, 64));
            float M = fmaxf(m_run[j], mx);
            float f = exp2f((m_run[j] - M) * LOG2E);
            m_run[j] = M;
            float p[4], sum = 0.f;
            #pragma unroll
            for (int n = 0; n < 4; ++n) {
                p[n] = exp2f((tt[n] - M) * LOG2E);
                sum += p[n];
            }
            #pragma unroll
            for (int w = 1; w <= 8; w <<= 1) sum += __shfl_xor(sum, w, 64);
            l_run[j] = l_run[j] * f + sum;
            #pragma unroll
            for (int n = 0; n < 4; ++n) O[n][j] *= f;
            int r = g * 4 + j;
            #pragma unroll
            for (int n = 0; n < 4; ++n)
                Pl[wave * 1024 + r * 64 + ((n * 16 + l15) ^ ((r & 7) << 3))] = f2bf(p[n]);
        }
        __syncthreads();   // Pl write -> read ordering

        // ---- O += P V
        #pragma unroll
        for (int c = 0; c < 2; ++c) {
            int pcol = c * 32 + g * 8;
            bf16x8 pa = *(const bf16x8*)(&Pl[wave * 1024 + swz(l15, pcol)]);
            #pragma unroll
            for (int n = 0; n < 4; ++n) {
                bf16x8 vb = *(const bf16x8*)(&Vt[swz(n * 16 + l15, pcol)]);
                O[n] = __builtin_amdgcn_mfma_f32_16x16x32_bf16(pa, vb, O[n], 0, 0, 0);
            }
        }
        __syncthreads();   // protect K/Vt before restage
    }

    // ---- epilogue
    const int hh = pr >> 1, bb = pr & 1;
    #pragma unroll
    for (int j = 0; j < 4; ++j) {
        float inv = 1.0f / l_run[j];
        int s = qt * QB + wave * 16 + g * 4 + j;
        float* op = out + (((size_t)(hh * S + s)) * 2 + bb) * 64;
        #pragma unroll
        for (int n = 0; n < 4; ++n) op[n * 16 + l15] = O[n][j] * inv;
    }
}

// ---------------- legacy fallback (round-6 verified kernel) for small ws_size
__global__ __launch_bounds__(256, 2) void attn_fwd(const float* __restrict__ x,
                                                   float* __restrict__ out) {
    __shared__ __align__(16) unsigned short Khi[KVB * D];
    __shared__ __align__(16) unsigned short Klo[KVB * D];
    __shared__ __align__(16) unsigned short Vt[D * KVB];
    __shared__ __align__(16) unsigned short Pl[4 * 16 * KVB];

    const int tid  = threadIdx.x;
    const int lane = tid & 63;
    const int wave = tid >> 6;
    const int l15  = lane & 15;
    const int g    = lane >> 4;
    const int pr = blockIdx.x & 31;
    const int qt = blockIdx.x >> 5;
    const float* __restrict__ base = x + (size_t)pr * (S * D);

    bf16x8 a_hi[2], a_lo[2];
    const int qrow = qt * QB + wave * 16 + l15;
    #pragma unroll
    for (int c = 0; c < 2; ++c) {
        const float* qp = base + qrow * D + c * 32 + g * 8;
        float4 q0 = *(const float4*)(qp);
        float4 q1 = *(const float4*)(qp + 4);
        float qv[8] = {q0.x, q0.y, q0.z, q0.w, q1.x, q1.y, q1.z, q1.w};
        bf16x8 hv, lv;
        #pragma unroll
        for (int i = 0; i < 8; ++i) {
            unsigned short hb = f2bf(qv[i]);
            hv[i] = (short)hb;
            lv[i] = (short)f2bf(qv[i] - bf2f(hb));
        }
        a_hi[c] = hv;
        a_lo[c] = lv;
    }

    f32x4 O[4];
    f32x4 zero4 = {0.f, 0.f, 0.f, 0.f};
    #pragma unroll
    for (int n = 0; n < 4; ++n) O[n] = zero4;
    float m_run[4] = {-INFINITY, -INFINITY, -INFINITY, -INFINITY};
    float l_run[4] = {0.f, 0.f, 0.f, 0.f};

    for (int kv = 0; kv < S; kv += KVB) {
        #pragma unroll
        for (int it = 0; it < 4; ++it) {
            int o = it * 1024 + tid * 4;
            int r = o >> 6;
            int c = o & 63;
            float4 v = *(const float4*)(base + (size_t)(kv + r) * D + c);
            float vv[4] = {v.x, v.y, v.z, v.w};
            unsigned short hb[4];
            bf16x4 hvv, lvv;
            #pragma unroll
            for (int i = 0; i < 4; ++i) {
                hb[i] = f2bf(vv[i]);
                hvv[i] = (short)hb[i];
                lvv[i] = (short)f2bf(vv[i] - bf2f(hb[i]));
            }
            int idx = swz(r, c);
            *(bf16x4*)(&Khi[idx]) = hvv;
            *(bf16x4*)(&Klo[idx]) = lvv;
            #pragma unroll
            for (int i = 0; i < 4; ++i) Vt[swz(c + i, r)] = hb[i];
        }
        __syncthreads();

        f32x4 st[4];
        #pragma unroll
        for (int n = 0; n < 4; ++n) {
            f32x4 acc = zero4;
            #pragma unroll
            for (int c = 0; c < 2; ++c) {
                int krow = n * 16 + l15;
                int col = c * 32 + g * 8;
                bf16x8 bh = *(const bf16x8*)(&Khi[swz(krow, col)]);
                bf16x8 bl = *(const bf16x8*)(&Klo[swz(krow, col)]);
                acc = __builtin_amdgcn_mfma_f32_16x16x32_bf16(a_lo[c], bh, acc, 0, 0, 0);
                acc = __builtin_amdgcn_mfma_f32_16x16x32_bf16(a_hi[c], bl, acc, 0, 0, 0);
                acc = __builtin_amdgcn_mfma_f32_16x16x32_bf16(a_hi[c], bh, acc, 0, 0, 0);
            }
            st[n] = acc;
        }

        #pragma unroll
        for (int j = 0; j < 4; ++j) {
            float tt[4];
            #pragma unroll
            for (int n = 0; n < 4; ++n) tt[n] = st[n][j] * SCALE;
            float mx = fmaxf(fmaxf(tt[0], tt[1]), fmaxf(tt[2], tt[3]));
            #pragma unroll
            for (int w = 1; w <= 8; w <<= 1) mx = fmaxf(mx, __shfl_xor(mx, w, 64));
            float M = fmaxf(m_run[j], mx);
            float f = exp2f((m_run[j] - M) * LOG2E);
            m_run[j] = M;
            float p[4], sum = 0.f;
            #pragma unroll
            for (int n = 0; n < 4; ++n) {
                p[n] = exp2f((tt[n] - M) * LOG2E);
                sum += p[n];
            }
            #pragma unroll
            for (int w = 1; w <= 8; w <<= 1) sum += __shfl_xor(sum, w, 64);
            l_run[j] = l_run[j] * f + sum;
            #pragma unroll
            for (int n = 0; n < 4; ++n) O[n][j] *= f;
            int r = g * 4 + j;
            #pragma unroll
            for (int n = 0; n < 4; ++n)
                Pl[wave * 1024 + r * 64 + ((n * 16 + l15) ^ ((r & 7) << 3))] = f2bf(p[n]);
        }
        __syncthreads();

        #pragma unroll
        for (int c = 0; c < 2; ++c) {
            int pcol = c * 32 + g * 8;
            bf16x8 pa = *(const bf16x8*)(&Pl[wave * 1024 + swz(l15, pcol)]);
            #pragma unroll
            for (int n = 0; n < 4; ++n) {
                bf16x8 vb = *(const bf16x8*)(&Vt[swz(n * 16 + l15, pcol)]);
                O[n] = __builtin_amdgcn_mfma_f32_16x16x32_bf16(pa, vb, O[n], 0, 0, 0);
            }
        }
        __syncthreads();
    }

    const int hh = pr >> 1, bb = pr & 1;
    #pragma unroll
    for (int j = 0; j < 4; ++j) {
        float inv = 1.0f / l_run[j];
        int s = qt * QB + wave * 16 + g * 4 + j;
        float* op = out + (((size_t)(hh * S + s)) * 2 + bb) * 64;
        #pragma unroll
        for (int n = 0; n < 4; ++n) op[n * 16 + l15] = O[n][j] * inv;
    }
}

extern "C" void kernel_launch(void* const* d_in, const int* in_sizes, int n_in,
                              void* d_out, int out_size, void* d_ws, size_t ws_size,
                              hipStream_t stream) {
    (void)in_sizes; (void)n_in; (void)out_size;
    const float* x = (const float*)d_in[0];
    float* out = (float*)d_out;
    if (ws_size >= WS_NEED) {
        unsigned short* Khi_g = (unsigned short*)d_ws;
        unsigned short* Klo_g = Khi_g + ARR;
        unsigned short* Vt_g  = Klo_g + ARR;
        prep_convert<<<dim3(1024), dim3(256), 0, stream>>>(x, Khi_g, Klo_g, Vt_g);
        attn_fwd2<<<dim3(1024), dim3(256), 0, stream>>>(Khi_g, Klo_g, Vt_g, out);
    } else {
        attn_fwd<<<dim3(1024), dim3(256), 0, stream>>>(x, out);
    }
}